// Round 9
// baseline (876.164 us; speedup 1.0000x reference)
//
#include <hip/hip_runtime.h>
#include <stdint.h>

// B=128 samples, C=512 channels, HW=1024 tokens.
// LN over full (C,HW) per sample; token-MLP: relu(t@w1^T+b1)@w2^T+b2.
// Input/output dtype detected at runtime (bf16 vs f32) via device-side flag.

#define NSAMP 128
#define CCH   512
#define HWSZ  1024
#define NPER  (CCH*HWSZ)   // 524288 elements per sample

typedef unsigned short u16;
typedef __bf16 bf16x8 __attribute__((ext_vector_type(8)));
typedef float  f32x4  __attribute__((ext_vector_type(4)));

__device__ __forceinline__ float b2f(u16 h){ return __uint_as_float(((unsigned)h)<<16); }
__device__ __forceinline__ u16 f2b(float f){
  unsigned u = __float_as_uint(f);
  u += 0x7FFFu + ((u>>16)&1u);   // RNE
  return (u16)(u>>16);
}
__device__ __forceinline__ void unpack8(uint4 v, float* f){
  const unsigned* u = (const unsigned*)&v;
#pragma unroll
  for (int q=0;q<4;q++){
    f[2*q]   = __uint_as_float(u[q]<<16);
    f[2*q+1] = __uint_as_float(u[q]&0xFFFF0000u);
  }
}
// dual-dtype 8-element loader; idx in ELEMENTS of the source dtype
__device__ __forceinline__ void load8(const void* base, size_t idx, int isf, float* f){
  if (isf){
    const float* p = (const float*)base + idx;
    uint4 a = *(const uint4*)p;
    uint4 b = *(const uint4*)(p+4);
    const float* af = (const float*)&a;
    const float* bf = (const float*)&b;
#pragma unroll
    for (int j=0;j<4;j++){ f[j]=af[j]; f[4+j]=bf[j]; }
  } else {
    uint4 v = *(const uint4*)((const u16*)base + idx);
    unpack8(v, f);
  }
}
__device__ __forceinline__ void store8b(u16* dst, const float* f){
  uint4 o; unsigned* ou = (unsigned*)&o;
#pragma unroll
  for (int q=0;q<4;q++) ou[q] = (unsigned)f2b(f[2*q]) | ((unsigned)f2b(f[2*q+1])<<16);
  *(uint4*)dst = o;
}

// async global->LDS, 16B per lane. LDS dest is wave-uniform-base + lane*16.
__device__ __forceinline__ void gload_lds16(const u16* g, u16* l){
  __builtin_amdgcn_global_load_lds(
      (const __attribute__((address_space(1))) void*)g,
      (__attribute__((address_space(3))) void*)l,
      16, 0, 0);
}

// ---------------- K0: dtype detect ----------------
__global__ __launch_bounds__(256) void detect_kernel(const u16* __restrict__ x,
                                                     int* __restrict__ flag){
  __shared__ int sh[256];
  int tid = threadIdx.x, cnt = 0;
  for (int i=tid; i<16384; i+=256){
    unsigned e = ((unsigned)x[i] >> 7) & 0xFFu;
    cnt += (e >= 0xC0u);
  }
  sh[tid] = cnt; __syncthreads();
  for (int s=128; s; s>>=1){ if (tid<s) sh[tid]+=sh[tid+s]; __syncthreads(); }
  if (tid==0) flag[0] = sh[0];
}

// ---------------- K0b: canonicalize weights/biases + LN params --------------
__global__ __launch_bounds__(256) void convert_kernel(
    const void* __restrict__ w1, const void* __restrict__ w2,
    const void* __restrict__ b1, const void* __restrict__ b2,
    const void* __restrict__ lw, const void* __restrict__ lb,
    const int* __restrict__ flag,
    u16* __restrict__ w1b, u16* __restrict__ w2b,
    float* __restrict__ b1f, float* __restrict__ b2f,
    u16* __restrict__ lwb, u16* __restrict__ lbb){
  int isf = flag[0] > 64;
  int t = blockIdx.x*256 + threadIdx.x;       // 256 blocks -> 65536 threads
  size_t i8 = (size_t)t*8;                    // covers 524288 elements
  float f[8];
  if (t < 32768){                             // w1/w2: 262144 elems each
    load8(w1, i8, isf, f); store8b(w1b + i8, f);
    load8(w2, i8, isf, f); store8b(w2b + i8, f);
  }
  load8(lw, i8, isf, f); store8b(lwb + i8, f);  // ln_w/ln_b: 524288 elems
  load8(lb, i8, isf, f); store8b(lbb + i8, f);
  if (t < 64){
    load8(b1, i8, isf, f);
#pragma unroll
    for (int j=0;j<8;j++) b1f[i8+j] = f[j];
    load8(b2, i8, isf, f);
#pragma unroll
    for (int j=0;j<8;j++) b2f[i8+j] = f[j];
  }
}

// ---------------- K1: per-sample sum / sumsq ----------------
__global__ __launch_bounds__(256) void stats_kernel(const void* __restrict__ x,
                                                    float* __restrict__ stats,
                                                    const int* __restrict__ flag){
  int isf = flag[0] > 64;
  int b   = blockIdx.y;
  int blk = blockIdx.x;                 // 16 blocks per sample
  size_t base = (size_t)b*NPER + (size_t)blk*32768;
  int tid = threadIdx.x;
  float s1 = 0.f, s2 = 0.f;
#pragma unroll
  for (int i=0;i<16;i++){
    float f[8];
    load8(x, base + i*2048 + tid*8, isf, f);
#pragma unroll
    for (int j=0;j<8;j++){ s1 += f[j]; s2 += f[j]*f[j]; }
  }
#pragma unroll
  for (int off=32; off; off>>=1){
    s1 += __shfl_down(s1, off);
    s2 += __shfl_down(s2, off);
  }
  __shared__ float r1[4], r2[4];
  int w = tid>>6, lane = tid&63;
  if (lane==0){ r1[w]=s1; r2[w]=s2; }
  __syncthreads();
  if (tid==0){
    atomicAdd(&stats[2*b],   r1[0]+r1[1]+r1[2]+r1[3]);
    atomicAdd(&stats[2*b+1], r2[0]+r2[1]+r2[2]+r2[3]);
  }
}

// ---------------- K2: LN + transpose to token-major xnT[s][c] (bf16) --------
// ln_w/ln_b pre-converted to bf16 (lwb/lbb) -> 2MB L2-resident, 2/3 the loads.
__global__ __launch_bounds__(256) void lnT_kernel(const void* __restrict__ x,
                                                  const u16* __restrict__ lwb,
                                                  const u16* __restrict__ lbb,
                                                  const float* __restrict__ stats,
                                                  const int* __restrict__ flag,
                                                  int gb0,
                                                  u16* __restrict__ xnT){
  int isf = flag[0] > 64;
  int bl = blockIdx.z;                  // group-local sample
  int gb = gb0 + bl;                    // global sample
  int c0 = blockIdx.y*64;
  int s0 = blockIdx.x*64;
  const float invN = 1.f/(float)NPER;
  float mu  = stats[2*gb]*invN;
  float var = fmaxf(stats[2*gb+1]*invN - mu*mu, 0.f);
  float rs  = rsqrtf(var + 1e-5f);

  __shared__ float T[64][65];           // [c][s], pad -> conflict-free transpose
  int tid = threadIdx.x;
  int tr  = tid>>3;                     // 0..31
  int tcl = (tid&7)*8;                  // 0..56

#pragma unroll
  for (int p=0;p<2;p++){
    int c = c0 + p*32 + tr;
    size_t idx = (size_t)c*HWSZ + s0 + tcl;
    float xf[8], wf[8], bf_[8];
    load8(x, (size_t)gb*NPER + idx, isf, xf);
    unpack8(*(const uint4*)(lwb + idx), wf);
    unpack8(*(const uint4*)(lbb + idx), bf_);
    float* dst = &T[p*32 + tr][tcl];
#pragma unroll
    for (int j=0;j<8;j++) dst[j] = (xf[j]-mu)*rs*wf[j] + bf_[j];
  }
  __syncthreads();
#pragma unroll
  for (int p=0;p<2;p++){
    int srow = p*32 + tr;
    float tmp[8];
#pragma unroll
    for (int j=0;j<8;j++) tmp[j] = T[tcl+j][srow];
    store8b(xnT + ((size_t)bl*HWSZ + s0 + srow)*CCH + c0 + tcl, tmp);
  }
}

// ---------------- K3/K4: NT GEMM, 256x256 tile, BK=64, counted-vmcnt dbuf ---
// C[m][n] = act( A[m][:] . B[n][:] + bias ), A,B row-major K-contiguous, K=512.
// 512 threads = 8 waves (2M x 4N); per-wave output 128x64; acc 8x4 f32x4.
// LDS 128KB: 2 buffers x (As[256][64] | Bs[256][64]) bf16.
// T4 counted vmcnt: inline-asm `s_waitcnt vmcnt(8)` + raw s_barrier keeps the
// NEXT tile's 8 global_load_lds in flight across the barrier during MFMAs.
// T2/rule-#21 chunk swizzle: LDS dest linear, global SOURCE chunk pre-XOR'd
// (c ^= row&7); fragment ds_read applies the same XOR -> conflict-free.
// Epilogue: restage C in LDS (bf16: 1 pass 128KB; f32: 2 passes of 128 rows),
// store coalesced 16B/lane.
template<int RELU, int BIASM, int MFIRST, int NOUT, int DUALOUT>
__global__ __launch_bounds__(512, 2) void gemm_kernel(
    const u16* __restrict__ A, long sA,
    const u16* __restrict__ B, long sB,
    const float* __restrict__ bias,
    u16* __restrict__ Co,
    const int* __restrict__ flag, int gb0)
{
  __shared__ __align__(16) u16 sh[65536];   // 128KB

  constexpr int NTN = NOUT/256;             // N tiles (GEMM1:2, GEMM2:4)
  constexpr int NTM = 8/NTN;                // M tiles (GEMM1:4, GEMM2:2)

  int b  = blockIdx.y;
  int bx = blockIdx.x;
  int tm, tn;
  if (MFIRST){ tm = bx % NTM; tn = bx / NTM; }
  else       { tn = bx % NTN; tm = bx / NTN; }
  const u16* Ab = A + (size_t)b*sA + (size_t)(tm*256)*512;
  const u16* Bb = B + (size_t)b*sB + (size_t)(tn*256)*512;

  int tid  = threadIdx.x;
  int lane = tid & 63;
  int w    = tid >> 6;                   // 0..7
  int wm   = w >> 2, wn = w & 3;         // 2M x 4N wave grid
  int l15  = lane & 15;
  int q    = lane >> 4;
  int sw   = l15 & 7;                    // = row&7 for this lane's frag rows

  // staging: 512 threads; per operand 4 issues of (64 rows x 128B).
  // row r = tid/8 + j*64, 16B chunk c_phys = tid%8; source k-chunk pre-XOR'd.
  int ar  = tid >> 3;                          // 0..63
  int acs = ((tid & 7) ^ (ar & 7)) * 8;        // element offset within BK
  const u16* aSrc = Ab + (size_t)ar*512 + acs;
  const u16* bSrc = Bb + (size_t)ar*512 + acs;

  f32x4 acc[8][4];
#pragma unroll
  for (int i=0;i<8;i++)
#pragma unroll
    for (int j=0;j<4;j++) acc[i][j] = (f32x4){0.f,0.f,0.f,0.f};

  // buffer p (0/1) at p*32768 elems; As first 16384 elems, Bs next 16384
  auto STAGE = [&](int p, int kk){
    u16* aD = sh + p*32768 + tid*8;
    u16* bD = sh + p*32768 + 16384 + tid*8;
#pragma unroll
    for (int j=0;j<4;j++) gload_lds16(aSrc + (size_t)j*32768 + kk, aD + j*4096);
#pragma unroll
    for (int j=0;j<4;j++) gload_lds16(bSrc + (size_t)j*32768 + kk, bD + j*4096);
  };
  auto COMPUTE = [&](int p){
    const u16* Asb = sh + p*32768;
    const u16* Bsb = Asb + 16384;
#pragma unroll
    for (int ks=0; ks<2; ks++){
      bf16x8 fa[8], fb[4];
      int pc = ((ks*4 + q) ^ sw) * 8;        // physical chunk (elements)
#pragma unroll
      for (int i=0;i<8;i++)
        fa[i] = *(const bf16x8*)(Asb + (wm*128 + i*16 + l15)*64 + pc);
#pragma unroll
      for (int jn=0;jn<4;jn++)
        fb[jn] = *(const bf16x8*)(Bsb + (wn*64 + jn*16 + l15)*64 + pc);
#pragma unroll
      for (int i=0;i<8;i++)
#pragma unroll
        for (int jn=0;jn<4;jn++)
          acc[i][jn] = __builtin_amdgcn_mfma_f32_16x16x32_bf16(fa[i], fb[jn], acc[i][jn], 0,0,0);
    }
  };

  // K-loop: tile t in buf t&1. Issue next tile's loads, then counted-wait for
  // CURRENT tile only (8 = next tile's loads still in flight across barrier).
  STAGE(0, 0);
#pragma unroll
  for (int t=0; t<7; t++){
    STAGE((t+1)&1, (t+1)*64);
    asm volatile("s_waitcnt vmcnt(8)" ::: "memory");  // tile t landed
    __builtin_amdgcn_s_barrier();                     // all waves see it
    __builtin_amdgcn_sched_barrier(0);                // no ds_read hoist (rule 18)
    COMPUTE(t & 1);
    __builtin_amdgcn_s_barrier();   // readers done before buf[t&1] overwrite @t+1
  }
  asm volatile("s_waitcnt vmcnt(0)" ::: "memory");
  __builtin_amdgcn_s_barrier();
  __builtin_amdgcn_sched_barrier(0);
  COMPUTE(1);                        // tile 7
  __syncthreads();                   // all MFMA LDS reads done before C-restage

  // ---- epilogue: C/D layout col(n)=lane&15, row(m)=(lane>>4)*4+reg ----
  int isf = DUALOUT ? (flag[0] > 64) : 0;
  size_t sampOff = (size_t)(gb0 + b) * NPER;
  int row0 = tm*256, col0 = tn*256;

  if (!DUALOUT || !isf){
    // bf16 out: stage 256x256 bf16 tile (128KB), XOR-swizzled 8-elem chunks
    u16* Cb = Co + sampOff;
#pragma unroll
    for (int i=0;i<8;i++){
#pragma unroll
      for (int jn=0;jn<4;jn++){
        int n = wn*64 + jn*16 + l15;
        float bn = BIASM ? 0.f : bias[col0 + n];
#pragma unroll
        for (int r=0;r<4;r++){
          int m = wm*128 + i*16 + q*4 + r;
          float v = acc[i][jn][r] + (BIASM ? bias[row0 + m] : bn);
          if (RELU) v = fmaxf(v, 0.f);
          sh[m*256 + (((n>>3) ^ (m&7))<<3) + (n&7)] = f2b(v);
        }
      }
    }
    __syncthreads();
    int rr = tid >> 1;                       // row 0..255
    int hf = (tid & 1)*16;                   // chunk half 0 / 16
#pragma unroll
    for (int j=0;j<16;j++){
      int c = hf + j;                        // logical chunk 0..31
      uint4 vv = *(const uint4*)(sh + rr*256 + ((c ^ (rr&7))<<3));
      *(uint4*)(Cb + (size_t)(row0+rr)*NOUT + col0 + (c<<3)) = vv;
    }
  } else {
    // f32 out: two passes of 128 rows x 256 cols (128KB each)
    float* Cf  = (float*)Co + sampOff;
    float* shf = (float*)sh;                 // [128][256] f32
#pragma unroll
    for (int p=0;p<2;p++){
      if (p) __syncthreads();                // readers of pass 0 done
      if (wm == p){
#pragma unroll
        for (int i=0;i<8;i++){
#pragma unroll
          for (int jn=0;jn<4;jn++){
            int n = wn*64 + jn*16 + l15;
            float bn = BIASM ? 0.f : bias[col0 + n];
#pragma unroll
            for (int r=0;r<4;r++){
              int ml = i*16 + q*4 + r;       // local row 0..127
              float v = acc[i][jn][r] + (BIASM ? bias[row0 + p*128 + ml] : bn);
              if (RELU) v = fmaxf(v, 0.f);
              // 4-float chunks, XOR-swizzled
              shf[ml*256 + (((n>>2) ^ (ml&7))<<2) + (n&3)] = v;
            }
          }
        }
      }
      __syncthreads();
      int rr = tid >> 2, qt = tid & 3;       // row 0..127, quarter 0..3
#pragma unroll
      for (int j=0;j<16;j++){
        int c = qt*16 + j;                   // logical f32 chunk 0..63
        uint4 vv = *(const uint4*)(shf + rr*256 + ((c ^ (rr&7))<<2));
        *(uint4*)(Cf + (size_t)(row0 + p*128 + rr)*NOUT + col0 + (c<<2)) = vv;
      }
    }
  }
}

extern "C" void kernel_launch(void* const* d_in, const int* in_sizes, int n_in,
                              void* d_out, int out_size, void* d_ws, size_t ws_size,
                              hipStream_t stream) {
  (void)in_sizes; (void)n_in; (void)out_size;
  const void* x  = d_in[0];
  const void* lw = d_in[1];
  const void* lb = d_in[2];
  const void* w1 = d_in[3];
  const void* b1 = d_in[4];
  const void* w2 = d_in[5];
  const void* b2 = d_in[6];

  char* ws = (char*)d_ws;
  float* stats = (float*)ws;                      // 256 floats
  int*   flag  = (int*)(ws + 1024);
  float* b1f   = (float*)(ws + 2048);
  float* b2f   = (float*)(ws + 4096);
  u16*   w1b   = (u16*)(ws + 8192);               // 512 KiB
  u16*   w2b   = (u16*)(ws + 8192 + 524288);      // 512 KiB (ends 1056768)
  u16*   lwb   = (u16*)(ws + 1179648);            // 1 MiB
  u16*   lbb   = (u16*)(ws + 1179648 + 1048576);  // 1 MiB (ends 3276800 < 4MiB)
  u16*   xnT   = (u16*)(ws + (size_t)(4u<<20));

  // adaptive group size: per sample xnT (1 MiB) + hdnT (1 MiB)
  long gmax = ((long)ws_size - (4L<<20)) / (2L<<20);
  int G = (int)(gmax < 1 ? 1 : (gmax > 128 ? 128 : gmax));
  u16* hdnT = xnT + (size_t)G*NPER;

  hipMemsetAsync(d_ws, 0, 2048, stream);
  detect_kernel<<<1,256,0,stream>>>((const u16*)x, flag);
  convert_kernel<<<256,256,0,stream>>>(w1, w2, b1, b2, lw, lb, flag,
                                       w1b, w2b, b1f, b2f, lwb, lbb);
  stats_kernel<<<dim3(16,NSAMP),256,0,stream>>>(x, stats, flag);

  for (int b0=0; b0<NSAMP; b0+=G){
    int Gi = (NSAMP-b0 < G) ? (NSAMP-b0) : G;
    lnT_kernel<<<dim3(HWSZ/64, CCH/64, Gi),256,0,stream>>>(x, lwb, lbb, stats, flag, b0, xnT);
    // GEMM1: M=1024(s) N=512(d) -> hdnT[s][d], relu, bias on n, always bf16
    gemm_kernel<1,0,1,512,0><<<dim3(8,Gi),512,0,stream>>>(
        xnT, (long)NPER, w1b, 0L, b1f, hdnT, flag, 0);
    // GEMM2: M=512(e) N=1024(s) -> out[e][s], bias on m, dtype per flag
    gemm_kernel<0,1,0,1024,1><<<dim3(8,Gi),512,0,stream>>>(
        w2b, 0L, hdnT, (long)NPER, b2f, (u16*)d_out, flag, b0);
  }
}

// Round 10
// 851.473 us; speedup vs baseline: 1.0290x; 1.0290x over previous
//
#include <hip/hip_runtime.h>
#include <stdint.h>

// B=128 samples, C=512 channels, HW=1024 tokens.
// LN over full (C,HW) per sample; token-MLP: relu(t@w1^T+b1)@w2^T+b2.
// Input/output dtype detected at runtime (bf16 vs f32) via device-side flag.

#define NSAMP 128
#define CCH   512
#define HWSZ  1024
#define NPER  (CCH*HWSZ)   // 524288 elements per sample

typedef unsigned short u16;
typedef __bf16 bf16x8 __attribute__((ext_vector_type(8)));
typedef float  f32x4  __attribute__((ext_vector_type(4)));

__device__ __forceinline__ float b2f(u16 h){ return __uint_as_float(((unsigned)h)<<16); }
__device__ __forceinline__ u16 f2b(float f){
  unsigned u = __float_as_uint(f);
  u += 0x7FFFu + ((u>>16)&1u);   // RNE
  return (u16)(u>>16);
}
__device__ __forceinline__ void unpack8(uint4 v, float* f){
  const unsigned* u = (const unsigned*)&v;
#pragma unroll
  for (int q=0;q<4;q++){
    f[2*q]   = __uint_as_float(u[q]<<16);
    f[2*q+1] = __uint_as_float(u[q]&0xFFFF0000u);
  }
}
// dual-dtype 8-element loader; idx in ELEMENTS of the source dtype
__device__ __forceinline__ void load8(const void* base, size_t idx, int isf, float* f){
  if (isf){
    const float* p = (const float*)base + idx;
    uint4 a = *(const uint4*)p;
    uint4 b = *(const uint4*)(p+4);
    const float* af = (const float*)&a;
    const float* bf = (const float*)&b;
#pragma unroll
    for (int j=0;j<4;j++){ f[j]=af[j]; f[4+j]=bf[j]; }
  } else {
    uint4 v = *(const uint4*)((const u16*)base + idx);
    unpack8(v, f);
  }
}
__device__ __forceinline__ void store8b(u16* dst, const float* f){
  uint4 o; unsigned* ou = (unsigned*)&o;
#pragma unroll
  for (int q=0;q<4;q++) ou[q] = (unsigned)f2b(f[2*q]) | ((unsigned)f2b(f[2*q+1])<<16);
  *(uint4*)dst = o;
}

// async global->LDS, 16B per lane. LDS dest is wave-uniform-base + lane*16.
__device__ __forceinline__ void gload_lds16(const u16* g, u16* l){
  __builtin_amdgcn_global_load_lds(
      (const __attribute__((address_space(1))) void*)g,
      (__attribute__((address_space(3))) void*)l,
      16, 0, 0);
}

// ---------------- K0: dtype detect ----------------
__global__ __launch_bounds__(256) void detect_kernel(const u16* __restrict__ x,
                                                     int* __restrict__ flag){
  __shared__ int sh[256];
  int tid = threadIdx.x, cnt = 0;
  for (int i=tid; i<16384; i+=256){
    unsigned e = ((unsigned)x[i] >> 7) & 0xFFu;
    cnt += (e >= 0xC0u);
  }
  sh[tid] = cnt; __syncthreads();
  for (int s=128; s; s>>=1){ if (tid<s) sh[tid]+=sh[tid+s]; __syncthreads(); }
  if (tid==0) flag[0] = sh[0];
}

// ---------------- K0b: canonicalize weights/biases + LN params --------------
__global__ __launch_bounds__(256) void convert_kernel(
    const void* __restrict__ w1, const void* __restrict__ w2,
    const void* __restrict__ b1, const void* __restrict__ b2,
    const void* __restrict__ lw, const void* __restrict__ lb,
    const int* __restrict__ flag,
    u16* __restrict__ w1b, u16* __restrict__ w2b,
    float* __restrict__ b1f, float* __restrict__ b2f,
    u16* __restrict__ lwb, u16* __restrict__ lbb){
  int isf = flag[0] > 64;
  int t = blockIdx.x*256 + threadIdx.x;       // 256 blocks -> 65536 threads
  size_t i8 = (size_t)t*8;                    // covers 524288 elements
  float f[8];
  if (t < 32768){                             // w1/w2: 262144 elems each
    load8(w1, i8, isf, f); store8b(w1b + i8, f);
    load8(w2, i8, isf, f); store8b(w2b + i8, f);
  }
  load8(lw, i8, isf, f); store8b(lwb + i8, f);  // ln_w/ln_b: 524288 elems
  load8(lb, i8, isf, f); store8b(lbb + i8, f);
  if (t < 64){
    load8(b1, i8, isf, f);
#pragma unroll
    for (int j=0;j<8;j++) b1f[i8+j] = f[j];
    load8(b2, i8, isf, f);
#pragma unroll
    for (int j=0;j<8;j++) b2f[i8+j] = f[j];
  }
}

// ---------------- K1: per-sample sum / sumsq ----------------
__global__ __launch_bounds__(256) void stats_kernel(const void* __restrict__ x,
                                                    float* __restrict__ stats,
                                                    const int* __restrict__ flag){
  int isf = flag[0] > 64;
  int b   = blockIdx.y;
  int blk = blockIdx.x;                 // 16 blocks per sample
  size_t base = (size_t)b*NPER + (size_t)blk*32768;
  int tid = threadIdx.x;
  float s1 = 0.f, s2 = 0.f;
#pragma unroll
  for (int i=0;i<16;i++){
    float f[8];
    load8(x, base + i*2048 + tid*8, isf, f);
#pragma unroll
    for (int j=0;j<8;j++){ s1 += f[j]; s2 += f[j]*f[j]; }
  }
#pragma unroll
  for (int off=32; off; off>>=1){
    s1 += __shfl_down(s1, off);
    s2 += __shfl_down(s2, off);
  }
  __shared__ float r1[4], r2[4];
  int w = tid>>6, lane = tid&63;
  if (lane==0){ r1[w]=s1; r2[w]=s2; }
  __syncthreads();
  if (tid==0){
    atomicAdd(&stats[2*b],   r1[0]+r1[1]+r1[2]+r1[3]);
    atomicAdd(&stats[2*b+1], r2[0]+r2[1]+r2[2]+r2[3]);
  }
}

// ---------------- K2: LN + transpose to token-major xnT[s][c] (bf16) --------
// ln_w/ln_b pre-converted to bf16 (lwb/lbb) -> 2MB L2-resident, 2/3 the loads.
__global__ __launch_bounds__(256) void lnT_kernel(const void* __restrict__ x,
                                                  const u16* __restrict__ lwb,
                                                  const u16* __restrict__ lbb,
                                                  const float* __restrict__ stats,
                                                  const int* __restrict__ flag,
                                                  int gb0,
                                                  u16* __restrict__ xnT){
  int isf = flag[0] > 64;
  int bl = blockIdx.z;                  // group-local sample
  int gb = gb0 + bl;                    // global sample
  int c0 = blockIdx.y*64;
  int s0 = blockIdx.x*64;
  const float invN = 1.f/(float)NPER;
  float mu  = stats[2*gb]*invN;
  float var = fmaxf(stats[2*gb+1]*invN - mu*mu, 0.f);
  float rs  = rsqrtf(var + 1e-5f);

  __shared__ float T[64][65];           // [c][s], pad -> conflict-free transpose
  int tid = threadIdx.x;
  int tr  = tid>>3;                     // 0..31
  int tcl = (tid&7)*8;                  // 0..56

#pragma unroll
  for (int p=0;p<2;p++){
    int c = c0 + p*32 + tr;
    size_t idx = (size_t)c*HWSZ + s0 + tcl;
    float xf[8], wf[8], bf_[8];
    load8(x, (size_t)gb*NPER + idx, isf, xf);
    unpack8(*(const uint4*)(lwb + idx), wf);
    unpack8(*(const uint4*)(lbb + idx), bf_);
    float* dst = &T[p*32 + tr][tcl];
#pragma unroll
    for (int j=0;j<8;j++) dst[j] = (xf[j]-mu)*rs*wf[j] + bf_[j];
  }
  __syncthreads();
#pragma unroll
  for (int p=0;p<2;p++){
    int srow = p*32 + tr;
    float tmp[8];
#pragma unroll
    for (int j=0;j<8;j++) tmp[j] = T[tcl+j][srow];
    store8b(xnT + ((size_t)bl*HWSZ + s0 + srow)*CCH + c0 + tcl, tmp);
  }
}

// ---------------- K3/K4: NT GEMM, 128x128 tile, BK=64, depth-2 prefetch -----
// C[m][n] = act( A[m][:] . B[n][:] + bias ), A,B row-major K-contiguous, K=512.
// ROUND-8 VERIFIED STRUCTURE + third staging buffer: tiles t+1 AND t+2 stay in
// flight (in-flight time ~2 phases >= L3/HBM latency ~900cy). Counted waits:
// vmcnt(16) in steady state (2x8 loads outstanding), 8 then 0 in the tail.
// 96KB LDS -> 1 block/CU; latency now covered within the block.
// T2/rule-#21 chunk swizzle: LDS dest linear, global SOURCE chunk pre-XOR'd
// (c ^= row&7); fragment ds_read applies the same XOR -> conflict-free.
// Epilogue: restage C in LDS, store coalesced 16B/lane (f32: single pass 64KB).
template<int RELU, int BIASM, int MFIRST, int NOUT, int DUALOUT>
__global__ __launch_bounds__(256) void gemm_kernel(
    const u16* __restrict__ A, long sA,
    const u16* __restrict__ B, long sB,
    const float* __restrict__ bias,
    u16* __restrict__ Co,
    const int* __restrict__ flag, int gb0)
{
  __shared__ __align__(16) u16 sh[49152];   // 96KB: 3x(As|Bs); reused for C

  int b  = blockIdx.y;
  int bx = blockIdx.x;
  int tm, tn;
  if (MFIRST){ tm = bx & 7; tn = bx >> 3; }
  else       { tn = bx & 7; tm = bx >> 3; }
  const u16* Ab = A + (size_t)b*sA + (size_t)(tm*128)*512;
  const u16* Bb = B + (size_t)b*sB + (size_t)(tn*128)*512;

  int tid  = threadIdx.x;
  int lane = tid & 63;
  int w    = tid >> 6;
  int wm   = w >> 1, wn = w & 1;
  int l15  = lane & 15;
  int q    = lane >> 4;
  int sw   = l15 & 7;                    // = row&7 for this lane's frag rows

  // staging source addressing (constant per thread across the K loop):
  // LDS slot for lane: row r = tid/8 (+ j*32), 16B chunk c_phys = tid%8.
  // source k-chunk = c_phys ^ (r&7)  (involution; undone on the read side)
  int ar  = tid >> 3;                          // 0..31
  int acs = ((tid & 7) ^ (ar & 7)) * 8;        // element offset within BK
  const u16* aSrc = Ab + (size_t)ar*512 + acs;
  const u16* bSrc = Bb + (size_t)ar*512 + acs;

  f32x4 acc[4][4];
#pragma unroll
  for (int i=0;i<4;i++)
#pragma unroll
    for (int j=0;j<4;j++) acc[i][j] = (f32x4){0.f,0.f,0.f,0.f};

  // buffer p in {0,1,2} at p*16384 elems; As first 8192, Bs next 8192
  auto STAGE = [&](int p, int kk){
    u16* aD = sh + p*16384 + tid*8;
    u16* bD = sh + p*16384 + 8192 + tid*8;
#pragma unroll
    for (int j=0;j<4;j++) gload_lds16(aSrc + j*16384 + kk, aD + j*2048);
#pragma unroll
    for (int j=0;j<4;j++) gload_lds16(bSrc + j*16384 + kk, bD + j*2048);
  };
  auto COMPUTE = [&](int p){
    const u16* Asb = sh + p*16384;
    const u16* Bsb = Asb + 8192;
#pragma unroll
    for (int ks=0; ks<2; ks++){
      bf16x8 fa[4], fb[4];
      int pc = ((ks*4 + q) ^ sw) * 8;        // physical chunk (elements)
#pragma unroll
      for (int i=0;i<4;i++){
        fa[i] = *(const bf16x8*)(Asb + (wm*64 + i*16 + l15)*64 + pc);
        fb[i] = *(const bf16x8*)(Bsb + (wn*64 + i*16 + l15)*64 + pc);
      }
#pragma unroll
      for (int i=0;i<4;i++)
#pragma unroll
        for (int jn=0;jn<4;jn++)
          acc[i][jn] = __builtin_amdgcn_mfma_f32_16x16x32_bf16(fa[i], fb[jn], acc[i][jn], 0,0,0);
    }
  };

  // K-loop, depth-2 prefetch over 3 buffers. Tile t lives in buf t%3.
  // At iter t: issue tile t+2; wait for tile t only (16 = tiles t+1,t+2 in
  // flight); compute; barrier. WAR: buf[(t+2)%3]=buf[(t-1)%3], readers done.
  STAGE(0, 0);
  STAGE(1, 64);
#pragma unroll
  for (int t=0; t<8; t++){
    if (t < 6) STAGE((t+2)%3, (t+2)*64);
    if (t < 6)      asm volatile("s_waitcnt vmcnt(16)" ::: "memory");
    else if (t == 6) asm volatile("s_waitcnt vmcnt(8)"  ::: "memory");
    else             asm volatile("s_waitcnt vmcnt(0)"  ::: "memory");
    __builtin_amdgcn_s_barrier();                     // all waves see tile t
    __builtin_amdgcn_sched_barrier(0);                // no ds_read hoist (rule 18)
    COMPUTE(t % 3);
    __builtin_amdgcn_s_barrier();   // readers done before buffer reuse
  }
  __syncthreads();                   // all MFMA LDS reads done before C-restage

  // ---- epilogue: C/D layout col(n)=lane&15, row(m)=(lane>>4)*4+reg ----
  int isf = DUALOUT ? (flag[0] > 64) : 0;
  size_t sampOff = (size_t)(gb0 + b) * NPER;
  int row0 = tm*128, col0 = tn*128;

  if (!DUALOUT || !isf){
    // bf16 out: stage full 128x128 tile (32KB), XOR-swizzled 8-elem chunks
    u16* Cb = Co + sampOff;
#pragma unroll
    for (int i=0;i<4;i++){
#pragma unroll
      for (int jn=0;jn<4;jn++){
        int n = wn*64 + jn*16 + l15;
        float bn = BIASM ? 0.f : bias[col0 + n];
#pragma unroll
        for (int r=0;r<4;r++){
          int m = wm*64 + i*16 + q*4 + r;
          float v = acc[i][jn][r] + (BIASM ? bias[row0 + m] : bn);
          if (RELU) v = fmaxf(v, 0.f);
          sh[m*128 + (n ^ ((m&7)<<3))] = f2b(v);
        }
      }
    }
    __syncthreads();
    int rr  = tid >> 1;                      // row 0..127
    int c0_ = (tid & 1)*8;                   // chunk base 0 / 8
#pragma unroll
    for (int j=0;j<8;j++){
      int c = c0_ + j;                       // logical chunk 0..15
      uint4 vv = *(const uint4*)(sh + rr*128 + ((c ^ (rr&7))<<3));
      *(uint4*)(Cb + (size_t)(row0+rr)*NOUT + col0 + (c<<3)) = vv;
    }
  } else {
    // f32 out: SINGLE pass, full 128x128 f32 tile (64KB of the 96KB LDS)
    float* Cf  = (float*)Co + sampOff;
    float* shf = (float*)sh;                 // [128][128] f32
#pragma unroll
    for (int i=0;i<4;i++){
#pragma unroll
      for (int jn=0;jn<4;jn++){
        int n = wn*64 + jn*16 + l15;
        float bn = BIASM ? 0.f : bias[col0 + n];
#pragma unroll
        for (int r=0;r<4;r++){
          int m = wm*64 + i*16 + q*4 + r;
          float v = acc[i][jn][r] + (BIASM ? bias[row0 + m] : bn);
          if (RELU) v = fmaxf(v, 0.f);
          // 4-float chunks, XOR-swizzled (XOR touches low 3 bits of chunk idx)
          shf[m*128 + (((n>>2) ^ (m&7))<<2) + (n&3)] = v;
        }
      }
    }
    __syncthreads();
    int rr = tid >> 1;                       // row 0..127
    int hf = (tid & 1)*16;                   // chunk half 0 / 16
#pragma unroll
    for (int j=0;j<16;j++){
      int c = hf + j;                        // logical f32 chunk 0..31
      uint4 vv = *(const uint4*)(shf + rr*128 + ((c ^ (rr&7))<<2));
      *(uint4*)(Cf + (size_t)(row0+rr)*NOUT + col0 + (c<<2)) = vv;
    }
  }
}

extern "C" void kernel_launch(void* const* d_in, const int* in_sizes, int n_in,
                              void* d_out, int out_size, void* d_ws, size_t ws_size,
                              hipStream_t stream) {
  (void)in_sizes; (void)n_in; (void)out_size;
  const void* x  = d_in[0];
  const void* lw = d_in[1];
  const void* lb = d_in[2];
  const void* w1 = d_in[3];
  const void* b1 = d_in[4];
  const void* w2 = d_in[5];
  const void* b2 = d_in[6];

  char* ws = (char*)d_ws;
  float* stats = (float*)ws;                      // 256 floats
  int*   flag  = (int*)(ws + 1024);
  float* b1f   = (float*)(ws + 2048);
  float* b2f   = (float*)(ws + 4096);
  u16*   w1b   = (u16*)(ws + 8192);               // 512 KiB
  u16*   w2b   = (u16*)(ws + 8192 + 524288);      // 512 KiB (ends 1056768)
  u16*   lwb   = (u16*)(ws + 1179648);            // 1 MiB
  u16*   lbb   = (u16*)(ws + 1179648 + 1048576);  // 1 MiB (ends 3276800 < 4MiB)
  u16*   xnT   = (u16*)(ws + (size_t)(4u<<20));

  // adaptive group size: per sample xnT (1 MiB) + hdnT (1 MiB)
  long gmax = ((long)ws_size - (4L<<20)) / (2L<<20);
  int G = (int)(gmax < 1 ? 1 : (gmax > 128 ? 128 : gmax));
  u16* hdnT = xnT + (size_t)G*NPER;

  hipMemsetAsync(d_ws, 0, 2048, stream);
  detect_kernel<<<1,256,0,stream>>>((const u16*)x, flag);
  convert_kernel<<<256,256,0,stream>>>(w1, w2, b1, b2, lw, lb, flag,
                                       w1b, w2b, b1f, b2f, lwb, lbb);
  stats_kernel<<<dim3(16,NSAMP),256,0,stream>>>(x, stats, flag);

  for (int b0=0; b0<NSAMP; b0+=G){
    int Gi = (NSAMP-b0 < G) ? (NSAMP-b0) : G;
    lnT_kernel<<<dim3(HWSZ/64, CCH/64, Gi),256,0,stream>>>(x, lwb, lbb, stats, flag, b0, xnT);
    // GEMM1: M=1024(s) N=512(d) -> hdnT[s][d], relu, bias on n, always bf16
    gemm_kernel<1,0,1,512,0><<<dim3(32,Gi),256,0,stream>>>(
        xnT, (long)NPER, w1b, 0L, b1f, hdnT, flag, 0);
    // GEMM2: M=512(e) N=1024(s) -> out[e][s], bias on m, dtype per flag
    gemm_kernel<0,1,0,1024,1><<<dim3(32,Gi),256,0,stream>>>(
        w2b, 0L, hdnT, (long)NPER, b2f, (u16*)d_out, flag, b0);
  }
}

// Round 13
// 775.078 us; speedup vs baseline: 1.1304x; 1.0986x over previous
//
#include <hip/hip_runtime.h>
#include <stdint.h>

// B=128 samples, C=512 channels, HW=1024 tokens.
// LN over full (C,HW) per sample; token-MLP: relu(t@w1^T+b1)@w2^T+b2.
// Input/output dtype detected at runtime (bf16 vs f32) via device-side flag.

#define NSAMP 128
#define CCH   512
#define HWSZ  1024
#define NPER  (CCH*HWSZ)   // 524288 elements per sample

typedef unsigned short u16;
typedef __bf16 bf16x8 __attribute__((ext_vector_type(8)));
typedef float  f32x4  __attribute__((ext_vector_type(4)));

__device__ __forceinline__ float b2f(u16 h){ return __uint_as_float(((unsigned)h)<<16); }
__device__ __forceinline__ u16 f2b(float f){
  unsigned u = __float_as_uint(f);
  u += 0x7FFFu + ((u>>16)&1u);   // RNE
  return (u16)(u>>16);
}
__device__ __forceinline__ void unpack8(uint4 v, float* f){
  const unsigned* u = (const unsigned*)&v;
#pragma unroll
  for (int q=0;q<4;q++){
    f[2*q]   = __uint_as_float(u[q]<<16);
    f[2*q+1] = __uint_as_float(u[q]&0xFFFF0000u);
  }
}
// dual-dtype 8-element loader; idx in ELEMENTS of the source dtype
__device__ __forceinline__ void load8(const void* base, size_t idx, int isf, float* f){
  if (isf){
    const float* p = (const float*)base + idx;
    uint4 a = *(const uint4*)p;
    uint4 b = *(const uint4*)(p+4);
    const float* af = (const float*)&a;
    const float* bf = (const float*)&b;
#pragma unroll
    for (int j=0;j<4;j++){ f[j]=af[j]; f[4+j]=bf[j]; }
  } else {
    uint4 v = *(const uint4*)((const u16*)base + idx);
    unpack8(v, f);
  }
}
__device__ __forceinline__ void store8b(u16* dst, const float* f){
  uint4 o; unsigned* ou = (unsigned*)&o;
#pragma unroll
  for (int q=0;q<4;q++) ou[q] = (unsigned)f2b(f[2*q]) | ((unsigned)f2b(f[2*q+1])<<16);
  *(uint4*)dst = o;
}

// async global->LDS, 16B per lane. LDS dest is wave-uniform-base + lane*16.
__device__ __forceinline__ void gload_lds16(const u16* g, u16* l){
  __builtin_amdgcn_global_load_lds(
      (const __attribute__((address_space(1))) void*)g,
      (__attribute__((address_space(3))) void*)l,
      16, 0, 0);
}

// ---------------- K0b: detect dtype (per-block local) + canonicalize --------
// bf16 N(0,1): exponent field never >= 0xC0. f32 read as u16 stream: low
// mantissa halves ~uniform -> ~25% have exp-field >= 0xC0.
__global__ __launch_bounds__(256) void convert_kernel(
    const void* __restrict__ w1, const void* __restrict__ w2,
    const void* __restrict__ b1, const void* __restrict__ b2,
    const void* __restrict__ lw, const void* __restrict__ lb,
    const void* __restrict__ x,
    int* __restrict__ flag,
    u16* __restrict__ w1b, u16* __restrict__ w2b,
    float* __restrict__ b1f, float* __restrict__ b2f,
    u16* __restrict__ lwb, u16* __restrict__ lbb){
  __shared__ int shc[256];
  int tid = threadIdx.x, cnt = 0;
  const u16* xv = (const u16*)x;
  for (int i=tid; i<16384; i+=256){
    unsigned e = ((unsigned)xv[i] >> 7) & 0xFFu;
    cnt += (e >= 0xC0u);
  }
  shc[tid] = cnt; __syncthreads();
  for (int s=128; s; s>>=1){ if (tid<s) shc[tid]+=shc[tid+s]; __syncthreads(); }
  int isf = shc[0] > 64;
  if (blockIdx.x==0 && tid==0) flag[0] = shc[0];   // publish for later kernels

  int t = blockIdx.x*256 + tid;               // 256 blocks -> 65536 threads
  size_t i8 = (size_t)t*8;                    // covers 524288 elements
  float f[8];
  if (t < 32768){                             // w1/w2: 262144 elems each
    load8(w1, i8, isf, f); store8b(w1b + i8, f);
    load8(w2, i8, isf, f); store8b(w2b + i8, f);
  }
  load8(lw, i8, isf, f); store8b(lwb + i8, f);  // ln_w/ln_b: 524288 elems
  load8(lb, i8, isf, f); store8b(lbb + i8, f);
  if (t < 64){
    load8(b1, i8, isf, f);
#pragma unroll
    for (int j=0;j<8;j++) b1f[i8+j] = f[j];
    load8(b2, i8, isf, f);
#pragma unroll
    for (int j=0;j<8;j++) b2f[i8+j] = f[j];
  }
}

// ---------------- K1: per-sample sum / sumsq ----------------
__global__ __launch_bounds__(256) void stats_kernel(const void* __restrict__ x,
                                                    float* __restrict__ stats,
                                                    const int* __restrict__ flag){
  int isf = flag[0] > 64;
  int b   = blockIdx.y;
  int blk = blockIdx.x;                 // 16 blocks per sample
  size_t base = (size_t)b*NPER + (size_t)blk*32768;
  int tid = threadIdx.x;
  float s1 = 0.f, s2 = 0.f;
#pragma unroll
  for (int i=0;i<16;i++){
    float f[8];
    load8(x, base + i*2048 + tid*8, isf, f);
#pragma unroll
    for (int j=0;j<8;j++){ s1 += f[j]; s2 += f[j]*f[j]; }
  }
#pragma unroll
  for (int off=32; off; off>>=1){
    s1 += __shfl_down(s1, off);
    s2 += __shfl_down(s2, off);
  }
  __shared__ float r1[4], r2[4];
  int w = tid>>6, lane = tid&63;
  if (lane==0){ r1[w]=s1; r2[w]=s2; }
  __syncthreads();
  if (tid==0){
    atomicAdd(&stats[2*b],   r1[0]+r1[1]+r1[2]+r1[3]);
    atomicAdd(&stats[2*b+1], r2[0]+r2[1]+r2[2]+r2[3]);
  }
}

// ---------------- K2: LN + transpose to token-major xnT[s][c] (bf16) --------
// ln_w/ln_b pre-converted to bf16 (lwb/lbb) -> 2MB L2-resident, 2/3 the loads.
__global__ __launch_bounds__(256) void lnT_kernel(const void* __restrict__ x,
                                                  const u16* __restrict__ lwb,
                                                  const u16* __restrict__ lbb,
                                                  const float* __restrict__ stats,
                                                  const int* __restrict__ flag,
                                                  int gb0,
                                                  u16* __restrict__ xnT){
  int isf = flag[0] > 64;
  int bl = blockIdx.z;                  // group-local sample
  int gb = gb0 + bl;                    // global sample
  int c0 = blockIdx.y*64;
  int s0 = blockIdx.x*64;
  const float invN = 1.f/(float)NPER;
  float mu  = stats[2*gb]*invN;
  float var = fmaxf(stats[2*gb+1]*invN - mu*mu, 0.f);
  float rs  = rsqrtf(var + 1e-5f);

  __shared__ float T[64][65];           // [c][s], pad -> conflict-free transpose
  int tid = threadIdx.x;
  int tr  = tid>>3;                     // 0..31
  int tcl = (tid&7)*8;                  // 0..56

#pragma unroll
  for (int p=0;p<2;p++){
    int c = c0 + p*32 + tr;
    size_t idx = (size_t)c*HWSZ + s0 + tcl;
    float xf[8], wf[8], bf_[8];
    load8(x, (size_t)gb*NPER + idx, isf, xf);
    unpack8(*(const uint4*)(lwb + idx), wf);
    unpack8(*(const uint4*)(lbb + idx), bf_);
    float* dst = &T[p*32 + tr][tcl];
#pragma unroll
    for (int j=0;j<8;j++) dst[j] = (xf[j]-mu)*rs*wf[j] + bf_[j];
  }
  __syncthreads();
#pragma unroll
  for (int p=0;p<2;p++){
    int srow = p*32 + tr;
    float tmp[8];
#pragma unroll
    for (int j=0;j<8;j++) tmp[j] = T[tcl+j][srow];
    store8b(xnT + ((size_t)bl*HWSZ + s0 + srow)*CCH + c0 + tcl, tmp);
  }
}

// ---------------- K3/K4: NT GEMM, 128x128 tile, BK=64, counted-vmcnt dbuf ---
// ROUND-8 VERIFIED STRUCTURE (166us GEMM2): double-buffered LDS (64KB -> 2
// blocks/CU — the co-resident block is the latency-hiding mechanism; rounds
// 9/10 proved 1-blk/CU variants regress). T4 counted vmcnt: inline-asm
// `s_waitcnt vmcnt(8)` + raw s_barrier so the NEXT tile's 8 global_load_lds
// stay in flight across the barrier while MFMAs run.
// T2/rule-#21 chunk swizzle: LDS dest linear, global SOURCE chunk pre-XOR'd
// (c ^= row&7); fragment ds_read applies the same XOR -> conflict-free.
// Epilogue: restage C in LDS, store coalesced 16B/lane (f32: single pass 64KB).
template<int RELU, int BIASM, int MFIRST, int NOUT, int DUALOUT>
__global__ __launch_bounds__(256) void gemm_kernel(
    const u16* __restrict__ A, long sA,
    const u16* __restrict__ B, long sB,
    const float* __restrict__ bias,
    u16* __restrict__ Co,
    const int* __restrict__ flag, int gb0)
{
  __shared__ __align__(16) u16 sh[32768];   // 64KB: 2x(As|Bs); reused for C

  int b  = blockIdx.y;
  int bx = blockIdx.x;
  int tm, tn;
  if (MFIRST){ tm = bx & 7; tn = bx >> 3; }
  else       { tn = bx & 7; tm = bx >> 3; }
  const u16* Ab = A + (size_t)b*sA + (size_t)(tm*128)*512;
  const u16* Bb = B + (size_t)b*sB + (size_t)(tn*128)*512;

  int tid  = threadIdx.x;
  int lane = tid & 63;
  int w    = tid >> 6;
  int wm   = w >> 1, wn = w & 1;
  int l15  = lane & 15;
  int q    = lane >> 4;
  int sw   = l15 & 7;                    // = row&7 for this lane's frag rows

  // staging source addressing (constant per thread across the K loop):
  // LDS slot for lane: row r = tid/8 (+ j*32), 16B chunk c_phys = tid%8.
  // source k-chunk = c_phys ^ (r&7)  (involution; undone on the read side)
  int ar  = tid >> 3;                          // 0..31
  int acs = ((tid & 7) ^ (ar & 7)) * 8;        // element offset within BK
  const u16* aSrc = Ab + (size_t)ar*512 + acs;
  const u16* bSrc = Bb + (size_t)ar*512 + acs;

  f32x4 acc[4][4];
#pragma unroll
  for (int i=0;i<4;i++)
#pragma unroll
    for (int j=0;j<4;j++) acc[i][j] = (f32x4){0.f,0.f,0.f,0.f};

  // p = buffer index (0/1); buffer p: As at p*16384, Bs at p*16384+8192
  auto STAGE = [&](int p, int kk){
    u16* aD = sh + p*16384 + tid*8;
    u16* bD = sh + p*16384 + 8192 + tid*8;
#pragma unroll
    for (int j=0;j<4;j++) gload_lds16(aSrc + j*16384 + kk, aD + j*2048);
#pragma unroll
    for (int j=0;j<4;j++) gload_lds16(bSrc + j*16384 + kk, bD + j*2048);
  };
  auto COMPUTE = [&](int p){
    const u16* Asb = sh + p*16384;
    const u16* Bsb = sh + p*16384 + 8192;
#pragma unroll
    for (int ks=0; ks<2; ks++){
      bf16x8 fa[4], fb[4];
      int pc = ((ks*4 + q) ^ sw) * 8;        // physical chunk (elements)
#pragma unroll
      for (int i=0;i<4;i++){
        fa[i] = *(const bf16x8*)(Asb + (wm*64 + i*16 + l15)*64 + pc);
        fb[i] = *(const bf16x8*)(Bsb + (wn*64 + i*16 + l15)*64 + pc);
      }
#pragma unroll
      for (int i=0;i<4;i++)
#pragma unroll
        for (int jn=0;jn<4;jn++)
          acc[i][jn] = __builtin_amdgcn_mfma_f32_16x16x32_bf16(fa[i], fb[jn], acc[i][jn], 0,0,0);
    }
  };

  // K-loop: tile t lives in buf t&1. Per iter: issue next tile's loads, then
  // counted-wait for CURRENT tile only (8 = next tile's loads still in flight).
  STAGE(0, 0);
#pragma unroll
  for (int t=0; t<7; t++){
    STAGE((t+1)&1, (t+1)*64);
    asm volatile("s_waitcnt vmcnt(8)" ::: "memory");  // tile t landed
    __builtin_amdgcn_s_barrier();                     // all waves see it
    __builtin_amdgcn_sched_barrier(0);                // no ds_read hoist (rule 18)
    COMPUTE(t & 1);
    __builtin_amdgcn_s_barrier();   // readers done before buf[t&1] overwrite @t+1
  }
  asm volatile("s_waitcnt vmcnt(0)" ::: "memory");
  __builtin_amdgcn_s_barrier();
  __builtin_amdgcn_sched_barrier(0);
  COMPUTE(1);                        // tile 7
  __syncthreads();                   // all MFMA LDS reads done before C-restage

  // ---- epilogue: C/D layout col(n)=lane&15, row(m)=(lane>>4)*4+reg ----
  int isf = DUALOUT ? (flag[0] > 64) : 0;
  size_t sampOff = (size_t)(gb0 + b) * NPER;
  int row0 = tm*128, col0 = tn*128;

  if (!DUALOUT || !isf){
    // bf16 out: stage full 128x128 tile (32KB), XOR-swizzled 8-elem chunks
    u16* Cb = Co + sampOff;
#pragma unroll
    for (int i=0;i<4;i++){
#pragma unroll
      for (int jn=0;jn<4;jn++){
        int n = wn*64 + jn*16 + l15;
        float bn = BIASM ? 0.f : bias[col0 + n];
#pragma unroll
        for (int r=0;r<4;r++){
          int m = wm*64 + i*16 + q*4 + r;
          float v = acc[i][jn][r] + (BIASM ? bias[row0 + m] : bn);
          if (RELU) v = fmaxf(v, 0.f);
          sh[m*128 + (n ^ ((m&7)<<3))] = f2b(v);
        }
      }
    }
    __syncthreads();
    int rr  = tid >> 1;                      // row 0..127
    int c0_ = (tid & 1)*8;                   // chunk base 0 / 8
#pragma unroll
    for (int j=0;j<8;j++){
      int c = c0_ + j;                       // logical chunk 0..15
      uint4 vv = *(const uint4*)(sh + rr*128 + ((c ^ (rr&7))<<3));
      *(uint4*)(Cb + (size_t)(row0+rr)*NOUT + col0 + (c<<3)) = vv;
    }
  } else {
    // f32 out: SINGLE pass, full 128x128 f32 tile in the 64KB LDS
    float* Cf  = (float*)Co + sampOff;
    float* shf = (float*)sh;                 // [128][128] f32
#pragma unroll
    for (int i=0;i<4;i++){
#pragma unroll
      for (int jn=0;jn<4;jn++){
        int n = wn*64 + jn*16 + l15;
        float bn = BIASM ? 0.f : bias[col0 + n];
#pragma unroll
        for (int r=0;r<4;r++){
          int m = wm*64 + i*16 + q*4 + r;
          float v = acc[i][jn][r] + (BIASM ? bias[row0 + m] : bn);
          if (RELU) v = fmaxf(v, 0.f);
          // 4-float chunks, XOR-swizzled (XOR touches low 3 bits of chunk idx)
          shf[m*128 + (((n>>2) ^ (m&7))<<2) + (n&3)] = v;
        }
      }
    }
    __syncthreads();
    int rr = tid >> 1;                       // row 0..127
    int hf = (tid & 1)*16;                   // chunk half 0 / 16
#pragma unroll
    for (int j=0;j<16;j++){
      int c = hf + j;                        // logical f32 chunk 0..31
      uint4 vv = *(const uint4*)(shf + rr*128 + ((c ^ (rr&7))<<2));
      *(uint4*)(Cf + (size_t)(row0+rr)*NOUT + col0 + (c<<2)) = vv;
    }
  }
}

extern "C" void kernel_launch(void* const* d_in, const int* in_sizes, int n_in,
                              void* d_out, int out_size, void* d_ws, size_t ws_size,
                              hipStream_t stream) {
  (void)in_sizes; (void)n_in; (void)out_size;
  const void* x  = d_in[0];
  const void* lw = d_in[1];
  const void* lb = d_in[2];
  const void* w1 = d_in[3];
  const void* b1 = d_in[4];
  const void* w2 = d_in[5];
  const void* b2 = d_in[6];

  char* ws = (char*)d_ws;
  float* stats = (float*)ws;                      // 256 floats
  int*   flag  = (int*)(ws + 1024);
  float* b1f   = (float*)(ws + 2048);
  float* b2f   = (float*)(ws + 4096);
  u16*   w1b   = (u16*)(ws + 8192);               // 512 KiB
  u16*   w2b   = (u16*)(ws + 8192 + 524288);      // 512 KiB (ends 1056768)
  u16*   lwb   = (u16*)(ws + 1179648);            // 1 MiB
  u16*   lbb   = (u16*)(ws + 1179648 + 1048576);  // 1 MiB (ends 3276800 < 4MiB)
  u16*   xnT   = (u16*)(ws + (size_t)(4u<<20));

  // adaptive group size: per sample xnT (1 MiB) + hdnT (1 MiB)
  long gmax = ((long)ws_size - (4L<<20)) / (2L<<20);
  int G = (int)(gmax < 1 ? 1 : (gmax > 128 ? 128 : gmax));
  u16* hdnT = xnT + (size_t)G*NPER;

  hipMemsetAsync(d_ws, 0, 2048, stream);
  convert_kernel<<<256,256,0,stream>>>(w1, w2, b1, b2, lw, lb, x, flag,
                                       w1b, w2b, b1f, b2f, lwb, lbb);
  stats_kernel<<<dim3(16,NSAMP),256,0,stream>>>(x, stats, flag);

  for (int b0=0; b0<NSAMP; b0+=G){
    int Gi = (NSAMP-b0 < G) ? (NSAMP-b0) : G;
    lnT_kernel<<<dim3(HWSZ/64, CCH/64, Gi),256,0,stream>>>(x, lwb, lbb, stats, flag, b0, xnT);
    // GEMM1: M=1024(s) N=512(d) -> hdnT[s][d], relu, bias on n, always bf16
    gemm_kernel<1,0,1,512,0><<<dim3(32,Gi),256,0,stream>>>(
        xnT, (long)NPER, w1b, 0L, b1f, hdnT, flag, 0);
    // GEMM2: M=512(e) N=1024(s) -> out[e][s], bias on m, dtype per flag
    gemm_kernel<0,1,0,1024,1><<<dim3(32,Gi),256,0,stream>>>(
        w2b, 0L, hdnT, (long)NPER, b2f, (u16*)d_out, flag, b0);
  }
}